// Round 1
// baseline (665.868 us; speedup 1.0000x reference)
//
#include <hip/hip_runtime.h>

#define N_NODES 50000
#define N_EDGES 100000
#define EDGE_DIM 8
#define EHID 32
#define DIN 32
#define H1 32
#define H2 64
#define NGRAPH 256
#define BN_EPS 1e-5f

// ---------------------------------------------------------------- utilities
__device__ inline void atomicMaxF(float* addr, float v) {
    // works with init = -inf; positive floats ordered as ints, negative reversed as uints
    if (v >= 0.0f) atomicMax((int*)addr, __float_as_int(v));
    else           atomicMin((unsigned int*)addr, __float_as_uint(v));
}

// ---------------------------------------------------------------- init
__global__ void init_kernel(float* agg1, float* agg2, float* gmax, float* gsum, float* gcnt) {
    int stride = gridDim.x * blockDim.x;
    int i0 = blockIdx.x * blockDim.x + threadIdx.x;
    for (int i = i0; i < N_NODES * H1; i += stride) agg1[i] = 0.0f;
    for (int i = i0; i < N_NODES * H2; i += stride) agg2[i] = 0.0f;
    for (int i = i0; i < NGRAPH * H2; i += stride) { gmax[i] = __int_as_float(0xff800000); gsum[i] = 0.0f; }
    for (int i = i0; i < NGRAPH; i += stride) gcnt[i] = 0.0f;
}

// ---------------------------------------------------------------- edge MLP layer 1 (h = relu(ea@w1+b1))
__global__ __launch_bounds__(256) void edge_hidden_kernel(
    const float* __restrict__ edge_attr, const float* __restrict__ w1,
    const float* __restrict__ b1, float* __restrict__ hout)
{
    __shared__ float s_w1[EDGE_DIM * EHID];
    __shared__ float s_b1[EHID];
    int tid = threadIdx.x;
    if (tid < EDGE_DIM * EHID) s_w1[tid] = w1[tid];
    if (tid < EHID) s_b1[tid] = b1[tid];
    __syncthreads();
    int e = blockIdx.x * 256 + tid;
    if (e >= N_EDGES) return;
    const float4* eap = reinterpret_cast<const float4*>(edge_attr + (size_t)e * EDGE_DIM);
    float4 v0 = eap[0], v1 = eap[1];
    float ea[EDGE_DIM] = {v0.x, v0.y, v0.z, v0.w, v1.x, v1.y, v1.z, v1.w};
    float* hp = hout + (size_t)e * EHID;
#pragma unroll
    for (int k4 = 0; k4 < EHID; k4 += 4) {
        float t[4];
#pragma unroll
        for (int q = 0; q < 4; ++q) {
            int k = k4 + q;
            float acc = s_b1[k];
#pragma unroll
            for (int j = 0; j < EDGE_DIM; ++j) acc += ea[j] * s_w1[j * EHID + k];
            t[q] = fmaxf(acc, 0.0f);
        }
        float4 r; r.x = t[0]; r.y = t[1]; r.z = t[2]; r.w = t[3];
        *reinterpret_cast<float4*>(hp + k4) = r;
    }
}

// ---------------------------------------------------------------- fused message + scatter
// msg[e,o] = sum_k h[e,k] * (sum_i g[e,i] * w2[k, i*DOUT+o])  + sum_i g[e,i]*b2[i*DOUT+o]
// handled as 33 k-slices (slice EHID == b2 with h==1).
template <int DOUT>
__global__ __launch_bounds__(256) void msg_kernel(
    const float* __restrict__ gsrc,   // node features [N, DIN]
    const float* __restrict__ hedge,  // [E, EHID]
    const int* __restrict__ src, const int* __restrict__ dst,
    const float* __restrict__ w2, const float* __restrict__ b2,
    float* __restrict__ agg)
{
    constexpr int OH = DOUT / 2;            // 2 output cols per thread: o, o+OH
    constexpr int TE = 2 * 256 / OH;        // edges per block (l1: 32, l2: 16)
    __shared__ float hs[TE * (EHID + 1)];   // padded stride 33 to dodge bank conflicts
    __shared__ float w2s[DIN * DOUT];
    int tid = threadIdx.x;
    int eBase = blockIdx.x * TE;

    for (int idx = tid; idx < TE * EHID; idx += 256)
        hs[(idx / EHID) * (EHID + 1) + (idx % EHID)] = hedge[(size_t)eBase * EHID + idx];

    int o0 = tid % OH;
    int eg = tid / OH;
    int e0 = eBase + eg * 2, e1 = e0 + 1;
    int s0 = src[e0], s1 = src[e1];

    float g0[DIN], g1[DIN];
#pragma unroll
    for (int i4 = 0; i4 < DIN; i4 += 4) {
        float4 a = *reinterpret_cast<const float4*>(gsrc + (size_t)s0 * DIN + i4);
        g0[i4] = a.x; g0[i4 + 1] = a.y; g0[i4 + 2] = a.z; g0[i4 + 3] = a.w;
        float4 b = *reinterpret_cast<const float4*>(gsrc + (size_t)s1 * DIN + i4);
        g1[i4] = b.x; g1[i4 + 1] = b.y; g1[i4 + 2] = b.z; g1[i4 + 3] = b.w;
    }

    float acc00 = 0.f, acc01 = 0.f, acc10 = 0.f, acc11 = 0.f;
    for (int k = 0; k <= EHID; ++k) {
        __syncthreads();
        const float* sp = (k < EHID) ? (w2 + (size_t)k * DIN * DOUT) : b2;
        for (int idx = tid * 4; idx < DIN * DOUT; idx += 256 * 4)
            *reinterpret_cast<float4*>(w2s + idx) = *reinterpret_cast<const float4*>(sp + idx);
        __syncthreads();
        float hv0 = (k < EHID) ? hs[(eg * 2) * (EHID + 1) + k] : 1.0f;
        float hv1 = (k < EHID) ? hs[(eg * 2 + 1) * (EHID + 1) + k] : 1.0f;
        float t00 = 0.f, t01 = 0.f, t10 = 0.f, t11 = 0.f;
#pragma unroll
        for (int i = 0; i < DIN; ++i) {
            float wv0 = w2s[i * DOUT + o0];
            float wv1 = w2s[i * DOUT + o0 + OH];
            t00 += g0[i] * wv0; t01 += g0[i] * wv1;
            t10 += g1[i] * wv0; t11 += g1[i] * wv1;
        }
        acc00 += hv0 * t00; acc01 += hv0 * t01;
        acc10 += hv1 * t10; acc11 += hv1 * t11;
    }
    int d0 = dst[e0], d1 = dst[e1];
    atomicAdd(&agg[(size_t)d0 * DOUT + o0],      acc00);
    atomicAdd(&agg[(size_t)d0 * DOUT + o0 + OH], acc01);
    atomicAdd(&agg[(size_t)d1 * DOUT + o0],      acc10);
    atomicAdd(&agg[(size_t)d1 * DOUT + o0 + OH], acc11);
}

// ---------------------------------------------------------------- node update: out = act(in@root + agg + bias)
template <int DOUTN, bool RELU>
__global__ __launch_bounds__(256) void node_update_kernel(
    const float* __restrict__ in, const float* __restrict__ root,
    const float* __restrict__ agg, const float* __restrict__ bias,
    float* __restrict__ out)
{
    constexpr int NPB = 256 / DOUTN;  // nodes per block
    __shared__ float roots[DIN * DOUTN];
    __shared__ float ins[NPB][DIN + 1];
    int tid = threadIdx.x;
    for (int idx = tid; idx < DIN * DOUTN; idx += 256) roots[idx] = root[idx];
    int nBase = blockIdx.x * NPB;
    for (int idx = tid; idx < NPB * DIN; idx += 256) {
        int nl = idx / DIN, i = idx % DIN;
        int n = nBase + nl;
        ins[nl][i] = (n < N_NODES) ? in[(size_t)n * DIN + i] : 0.0f;
    }
    __syncthreads();
    int o = tid % DOUTN, nl = tid / DOUTN;
    int n = nBase + nl;
    if (n >= N_NODES) return;
    float t = agg[(size_t)n * DOUTN + o] + bias[o];
#pragma unroll
    for (int i = 0; i < DIN; ++i) t += ins[nl][i] * roots[i * DOUTN + o];
    if (RELU) t = fmaxf(t, 0.0f);
    out[(size_t)n * DOUTN + o] = t;
}

// ---------------------------------------------------------------- pooling (max + sum + count)
__global__ __launch_bounds__(256) void pool_kernel(
    const float* __restrict__ h, const int* __restrict__ batch,
    float* gmax, float* gsum, float* gcnt)
{
    int idx = blockIdx.x * 256 + threadIdx.x;
    if (idx >= N_NODES * H2) return;
    int n = idx / H2, f = idx % H2;
    int b = batch[n];
    float v = h[idx];
    atomicMaxF(&gmax[b * H2 + f], v);
    atomicAdd(&gsum[b * H2 + f], v);
    if (f == 0) atomicAdd(&gcnt[b], 1.0f);
}

// ---------------------------------------------------------------- MLP head (one block per graph)
__global__ __launch_bounds__(128) void head_kernel(
    const float* __restrict__ gmax, const float* __restrict__ gsum, const float* __restrict__ gcnt,
    const float* __restrict__ h1w, const float* __restrict__ h1b,
    const float* __restrict__ bn1g, const float* __restrict__ bn1b,
    const float* __restrict__ bn1m, const float* __restrict__ bn1v,
    const float* __restrict__ h2w, const float* __restrict__ h2b,
    const float* __restrict__ bn2g, const float* __restrict__ bn2b,
    const float* __restrict__ bn2m, const float* __restrict__ bn2v,
    const float* __restrict__ h3w, const float* __restrict__ h3b,
    float* __restrict__ out)
{
    __shared__ float feat[2 * H2];
    __shared__ float z1s[H2];
    __shared__ float z2s[H2 / 2];
    int b = blockIdx.x, tid = threadIdx.x;
    float cnt = fmaxf(gcnt[b], 1.0f);
    if (tid < H2) feat[tid] = gmax[b * H2 + tid];
    else          feat[tid] = gsum[b * H2 + (tid - H2)] / cnt;
    __syncthreads();
    if (tid < H2) {
        float acc = h1b[tid];
#pragma unroll
        for (int j = 0; j < 2 * H2; ++j) acc += feat[j] * h1w[j * H2 + tid];
        acc = (acc - bn1m[tid]) * rsqrtf(bn1v[tid] + BN_EPS) * bn1g[tid] + bn1b[tid];
        z1s[tid] = fmaxf(acc, 0.0f);
    }
    __syncthreads();
    if (tid < H2 / 2) {
        float acc = h2b[tid];
#pragma unroll
        for (int j = 0; j < H2; ++j) acc += z1s[j] * h2w[j * (H2 / 2) + tid];
        acc = (acc - bn2m[tid]) * rsqrtf(bn2v[tid] + BN_EPS) * bn2g[tid] + bn2b[tid];
        z2s[tid] = fmaxf(acc, 0.0f);
    }
    __syncthreads();
    if (tid == 0) {
        float acc = h3b[0];
#pragma unroll
        for (int j = 0; j < H2 / 2; ++j) acc += z2s[j] * h3w[j];
        out[b] = acc;
    }
}

// ---------------------------------------------------------------- launch
extern "C" void kernel_launch(void* const* d_in, const int* in_sizes, int n_in,
                              void* d_out, int out_size, void* d_ws, size_t ws_size,
                              hipStream_t stream)
{
    const float* x         = (const float*)d_in[0];
    const int*   ei        = (const int*)d_in[1];
    const float* edge_attr = (const float*)d_in[2];
    const int*   batch     = (const int*)d_in[3];
    const float* e1_w1 = (const float*)d_in[4];
    const float* e1_b1 = (const float*)d_in[5];
    const float* e1_w2 = (const float*)d_in[6];
    const float* e1_b2 = (const float*)d_in[7];
    const float* root1 = (const float*)d_in[8];
    const float* bias1 = (const float*)d_in[9];
    const float* e2_w1 = (const float*)d_in[10];
    const float* e2_b1 = (const float*)d_in[11];
    const float* e2_w2 = (const float*)d_in[12];
    const float* e2_b2 = (const float*)d_in[13];
    const float* root2 = (const float*)d_in[14];
    const float* bias2 = (const float*)d_in[15];
    const float* h1w = (const float*)d_in[16];
    const float* h1b = (const float*)d_in[17];
    const float* bn1g = (const float*)d_in[18];
    const float* bn1b = (const float*)d_in[19];
    const float* bn1m = (const float*)d_in[20];
    const float* bn1v = (const float*)d_in[21];
    const float* h2w = (const float*)d_in[22];
    const float* h2b = (const float*)d_in[23];
    const float* bn2g = (const float*)d_in[24];
    const float* bn2b = (const float*)d_in[25];
    const float* bn2m = (const float*)d_in[26];
    const float* bn2v = (const float*)d_in[27];
    const float* h3w = (const float*)d_in[28];
    const float* h3b = (const float*)d_in[29];
    float* out = (float*)d_out;

    float* ws = (float*)d_ws;
    float* hedge = ws;                                  // E*EHID (reused by both layers)
    float* out1  = hedge + (size_t)N_EDGES * EHID;      // N*H1
    float* agg1  = out1 + (size_t)N_NODES * H1;         // N*H1
    float* agg2  = agg1 + (size_t)N_NODES * H1;         // N*H2
    float* h2o   = agg2 + (size_t)N_NODES * H2;         // N*H2
    float* gmaxb = h2o + (size_t)N_NODES * H2;          // NGRAPH*H2
    float* gsumb = gmaxb + NGRAPH * H2;                 // NGRAPH*H2
    float* gcntb = gsumb + NGRAPH * H2;                 // NGRAPH

    const int* srcp = ei;
    const int* dstp = ei + N_EDGES;

    init_kernel<<<2048, 256, 0, stream>>>(agg1, agg2, gmaxb, gsumb, gcntb);

    // layer 1
    edge_hidden_kernel<<<(N_EDGES + 255) / 256, 256, 0, stream>>>(edge_attr, e1_w1, e1_b1, hedge);
    msg_kernel<H1><<<N_EDGES / 32, 256, 0, stream>>>(x, hedge, srcp, dstp, e1_w2, e1_b2, agg1);
    node_update_kernel<H1, true><<<N_NODES / 8, 256, 0, stream>>>(x, root1, agg1, bias1, out1);

    // layer 2
    edge_hidden_kernel<<<(N_EDGES + 255) / 256, 256, 0, stream>>>(edge_attr, e2_w1, e2_b1, hedge);
    msg_kernel<H2><<<N_EDGES / 16, 256, 0, stream>>>(out1, hedge, srcp, dstp, e2_w2, e2_b2, agg2);
    node_update_kernel<H2, false><<<N_NODES / 4, 256, 0, stream>>>(out1, root2, agg2, bias2, h2o);

    // pooling + head
    pool_kernel<<<(N_NODES * H2 + 255) / 256, 256, 0, stream>>>(h2o, batch, gmaxb, gsumb, gcntb);
    head_kernel<<<NGRAPH, 128, 0, stream>>>(gmaxb, gsumb, gcntb,
                                            h1w, h1b, bn1g, bn1b, bn1m, bn1v,
                                            h2w, h2b, bn2g, bn2b, bn2m, bn2v,
                                            h3w, h3b, out);
}

// Round 2
// 151.843 us; speedup vs baseline: 4.3852x; 4.3852x over previous
//
#include <hip/hip_runtime.h>

#define N_NODES 50000
#define N_EDGES 100000
#define EDGE_DIM 8
#define EHID 32
#define DIN 32
#define H1 32
#define H2 64
#define NGRAPH 256
#define BN_EPS 1e-5f
#define KTOT 1056   // EHID*DIN + DIN (b2 rows appended)

typedef __attribute__((ext_vector_type(8))) short bf16x8;
typedef __attribute__((ext_vector_type(4))) float f32x4;

// ---------------------------------------------------------------- utilities
__device__ inline void atomicMaxF(float* addr, float v) {
    if (v >= 0.0f) atomicMax((int*)addr, __float_as_int(v));
    else           atomicMin((unsigned int*)addr, __float_as_uint(v));
}

__device__ inline unsigned short f2bf_rne(float f) {
    unsigned int u = __float_as_uint(f);
    u += 0x7fffu + ((u >> 16) & 1u);
    return (unsigned short)(u >> 16);
}

// ---------------------------------------------------------------- init
__global__ void init_kernel(float* agg1, float* agg2, float* gmax, float* gsum, float* gcnt) {
    int stride = gridDim.x * blockDim.x;
    int i0 = blockIdx.x * blockDim.x + threadIdx.x;
    for (int i = i0; i < N_NODES * H1; i += stride) agg1[i] = 0.0f;
    for (int i = i0; i < N_NODES * H2; i += stride) agg2[i] = 0.0f;
    for (int i = i0; i < NGRAPH * H2; i += stride) { gmax[i] = __int_as_float(0xff800000); gsum[i] = 0.0f; }
    for (int i = i0; i < NGRAPH; i += stride) gcnt[i] = 0.0f;
}

// ---------------------------------------------------------------- prep: w2 (fp32 [EH, DIN*DOUT]) + b2 -> w2t bf16 [DOUT][KTOT]
// k < 1024: km = k>>5, i = k&31 -> w2[km][i*DOUT+o];  k >= 1024: i = k-1024 -> b2[i*DOUT+o]
__global__ __launch_bounds__(256) void prep_w2t_kernel(
    const float* __restrict__ w2_1, const float* __restrict__ b2_1,
    const float* __restrict__ w2_2, const float* __restrict__ b2_2,
    unsigned short* __restrict__ w2t1, unsigned short* __restrict__ w2t2)
{
    int idx = blockIdx.x * 256 + threadIdx.x;
    const int n1 = H1 * KTOT;
    const int n2 = H2 * KTOT;
    if (idx < n1) {
        int o = idx / KTOT, k = idx % KTOT;
        float v;
        if (k < EHID * DIN) v = w2_1[(k >> 5) * (DIN * H1) + (k & 31) * H1 + o];
        else                v = b2_1[(k - EHID * DIN) * H1 + o];
        w2t1[idx] = f2bf_rne(v);
    } else if (idx < n1 + n2) {
        int j = idx - n1;
        int o = j / KTOT, k = j % KTOT;
        float v;
        if (k < EHID * DIN) v = w2_2[(k >> 5) * (DIN * H2) + (k & 31) * H2 + o];
        else                v = b2_2[(k - EHID * DIN) * H2 + o];
        w2t2[j] = f2bf_rne(v);
    }
}

// ---------------------------------------------------------------- edge MLP (h = relu(ea@w1+b1))
__global__ __launch_bounds__(256) void edge_hidden_kernel(
    const float* __restrict__ edge_attr, const float* __restrict__ w1,
    const float* __restrict__ b1, float* __restrict__ hout)
{
    __shared__ float s_w1[EDGE_DIM * EHID];
    __shared__ float s_b1[EHID];
    int tid = threadIdx.x;
    if (tid < EDGE_DIM * EHID) s_w1[tid] = w1[tid];
    if (tid < EHID) s_b1[tid] = b1[tid];
    __syncthreads();
    int e = blockIdx.x * 256 + tid;
    if (e >= N_EDGES) return;
    const float4* eap = reinterpret_cast<const float4*>(edge_attr + (size_t)e * EDGE_DIM);
    float4 v0 = eap[0], v1 = eap[1];
    float ea[EDGE_DIM] = {v0.x, v0.y, v0.z, v0.w, v1.x, v1.y, v1.z, v1.w};
    float* hp = hout + (size_t)e * EHID;
#pragma unroll
    for (int k4 = 0; k4 < EHID; k4 += 4) {
        float t[4];
#pragma unroll
        for (int q = 0; q < 4; ++q) {
            int k = k4 + q;
            float acc = s_b1[k];
#pragma unroll
            for (int j = 0; j < EDGE_DIM; ++j) acc += ea[j] * s_w1[j * EHID + k];
            t[q] = fmaxf(acc, 0.0f);
        }
        float4 r; r.x = t[0]; r.y = t[1]; r.z = t[2]; r.w = t[3];
        *reinterpret_cast<float4*>(hp + k4) = r;
    }
}

// ---------------------------------------------------------------- MFMA message + scatter
// GEMM: msg[E, DOUT] = U[E, KTOT] @ B[KTOT, DOUT], U[e, km*32+i] = h[e,km]*g[e,i] (km=32 => h=1, g*b2)
// A-frag formed in registers; B staged per 32-k slice in LDS (bf16, padded rows).
template <int DOUT>
__global__ __launch_bounds__(256) void msg_mfma_kernel(
    const float* __restrict__ gsrc,           // [N, 32] source-node features
    const float* __restrict__ hedge,          // [E, 32]
    const int* __restrict__ src, const int* __restrict__ dst,
    const unsigned short* __restrict__ w2t,   // bf16 [DOUT][KTOT]
    float* __restrict__ agg)                  // [N, DOUT]
{
    constexpr int NT = DOUT / 16;   // output col tiles per wave
    constexpr int EB = 64;          // edges per block (4 waves x 16)
    constexpr int SB = 40;          // b_lds row stride (bf16): 32 + 8 pad -> bank step 20
    __shared__ float h_lds[EB][33];
    __shared__ __align__(16) unsigned short b_lds[DOUT][SB];

    const int tid = threadIdx.x;
    const int wave = tid >> 6;
    const int lane = tid & 63;
    const int eBase = blockIdx.x * EB;

    // stage h (64 edges x 32), zero-pad OOB edges
    for (int idx = tid; idx < EB * EHID; idx += 256) {
        int e = idx >> 5, k = idx & 31;
        float v = (eBase + e < N_EDGES) ? hedge[(size_t)(eBase + e) * EHID + k] : 0.0f;
        h_lds[e][k] = v;
    }

    // per-lane fixed g fragment: edge = eBase + wave*16 + (lane&15), i = (lane>>4)*8 + j
    const int erow = lane & 15;
    const int kq = lane >> 4;
    const int myE = eBase + wave * 16 + erow;
    float g[8];
    if (myE < N_EDGES) {
        int s = src[myE];
        const float4* gp = reinterpret_cast<const float4*>(gsrc + (size_t)s * DIN + kq * 8);
        float4 a = gp[0], b = gp[1];
        g[0] = a.x; g[1] = a.y; g[2] = a.z; g[3] = a.w;
        g[4] = b.x; g[5] = b.y; g[6] = b.z; g[7] = b.w;
    } else {
#pragma unroll
        for (int j = 0; j < 8; ++j) g[j] = 0.0f;
    }

    // stage B slice 0: thread t -> o = t>>2, 16B chunk = t&3
    const int so = tid >> 2, sc = tid & 3;
    const bool stager = (so < DOUT);
    if (stager) {
        *reinterpret_cast<float4*>(&b_lds[so][sc * 8]) =
            *reinterpret_cast<const float4*>(w2t + (size_t)so * KTOT + sc * 8);
    }
    __syncthreads();

    f32x4 acc[NT];
#pragma unroll
    for (int t = 0; t < NT; ++t) acc[t] = (f32x4){0.f, 0.f, 0.f, 0.f};

    const int NSLICE = KTOT / 32;   // 33
    for (int kk = 0; kk < NSLICE; ++kk) {
        // prefetch next slice to regs (hides L2 latency under compute)
        float4 nxt;
        if (stager && kk + 1 < NSLICE) {
            nxt = *reinterpret_cast<const float4*>(w2t + (size_t)so * KTOT + (kk + 1) * 32 + sc * 8);
        }

        float hv = (kk < EHID) ? h_lds[wave * 16 + erow][kk] : 1.0f;

        // A fragment = bf16(hv * g[j])
        unsigned int a0, a1, a2, a3;
        asm("v_cvt_pk_bf16_f32 %0, %1, %2" : "=v"(a0) : "v"(hv * g[0]), "v"(hv * g[1]));
        asm("v_cvt_pk_bf16_f32 %0, %1, %2" : "=v"(a1) : "v"(hv * g[2]), "v"(hv * g[3]));
        asm("v_cvt_pk_bf16_f32 %0, %1, %2" : "=v"(a2) : "v"(hv * g[4]), "v"(hv * g[5]));
        asm("v_cvt_pk_bf16_f32 %0, %1, %2" : "=v"(a3) : "v"(hv * g[6]), "v"(hv * g[7]));
        union { unsigned int u[4]; bf16x8 v; } afu;
        afu.u[0] = a0; afu.u[1] = a1; afu.u[2] = a2; afu.u[3] = a3;

#pragma unroll
        for (int t = 0; t < NT; ++t) {
            bf16x8 bfrag = *reinterpret_cast<const bf16x8*>(&b_lds[t * 16 + erow][kq * 8]);
            acc[t] = __builtin_amdgcn_mfma_f32_16x16x32_bf16(afu.v, bfrag, acc[t], 0, 0, 0);
        }

        __syncthreads();
        if (stager && kk + 1 < NSLICE) {
            *reinterpret_cast<float4*>(&b_lds[so][sc * 8]) = nxt;
        }
        __syncthreads();
    }

    // scatter: C/D mapping col = lane&15, row = (lane>>4)*4 + r
#pragma unroll
    for (int r = 0; r < 4; ++r) {
        int el = kq * 4 + r;
        int e = eBase + wave * 16 + el;
        if (e < N_EDGES) {
            int d = dst[e];
#pragma unroll
            for (int t = 0; t < NT; ++t)
                atomicAdd(&agg[(size_t)d * DOUT + t * 16 + erow], acc[t][r]);
        }
    }
}

// ---------------------------------------------------------------- node update: out = act(in@root + agg + bias)
template <int DOUTN, bool RELU>
__global__ __launch_bounds__(256) void node_update_kernel(
    const float* __restrict__ in, const float* __restrict__ root,
    const float* __restrict__ agg, const float* __restrict__ bias,
    float* __restrict__ out)
{
    constexpr int NPB = 256 / DOUTN;
    __shared__ float roots[DIN * DOUTN];
    __shared__ float ins[NPB][DIN + 1];
    int tid = threadIdx.x;
    for (int idx = tid; idx < DIN * DOUTN; idx += 256) roots[idx] = root[idx];
    int nBase = blockIdx.x * NPB;
    for (int idx = tid; idx < NPB * DIN; idx += 256) {
        int nl = idx / DIN, i = idx % DIN;
        int n = nBase + nl;
        ins[nl][i] = (n < N_NODES) ? in[(size_t)n * DIN + i] : 0.0f;
    }
    __syncthreads();
    int o = tid % DOUTN, nl = tid / DOUTN;
    int n = nBase + nl;
    if (n >= N_NODES) return;
    float t = agg[(size_t)n * DOUTN + o] + bias[o];
#pragma unroll
    for (int i = 0; i < DIN; ++i) t += ins[nl][i] * roots[i * DOUTN + o];
    if (RELU) t = fmaxf(t, 0.0f);
    out[(size_t)n * DOUTN + o] = t;
}

// ---------------------------------------------------------------- pooling: sorted-run scan (batch_index sorted)
// block: 64 nodes; thread (r = tid>>6, o = tid&63) scans 16 contiguous nodes for col o.
__global__ __launch_bounds__(256) void pool_scan_kernel(
    const float* __restrict__ h, const int* __restrict__ batch,
    float* gmax, float* gsum, float* gcnt)
{
    __shared__ int s_batch[64];
    int tid = threadIdx.x;
    int base = blockIdx.x * 64;
    if (tid < 64) s_batch[tid] = (base + tid < N_NODES) ? batch[base + tid] : -1;
    __syncthreads();
    int o = tid & 63, r = tid >> 6;
    int curb = -1; float s = 0.f, m = __int_as_float(0xff800000); float c = 0.f;
#pragma unroll
    for (int j = 0; j < 16; ++j) {
        int n = base + r * 16 + j;
        if (n >= N_NODES) break;
        int b = s_batch[r * 16 + j];
        if (b != curb) {
            if (curb >= 0) {
                atomicAdd(&gsum[curb * H2 + o], s);
                atomicMaxF(&gmax[curb * H2 + o], m);
                if (o == 0) atomicAdd(&gcnt[curb], c);
            }
            curb = b; s = 0.f; m = __int_as_float(0xff800000); c = 0.f;
        }
        float v = h[(size_t)n * H2 + o];
        s += v; m = fmaxf(m, v); c += 1.f;
    }
    if (curb >= 0) {
        atomicAdd(&gsum[curb * H2 + o], s);
        atomicMaxF(&gmax[curb * H2 + o], m);
        if (o == 0) atomicAdd(&gcnt[curb], c);
    }
}

// ---------------------------------------------------------------- MLP head (one block per graph)
__global__ __launch_bounds__(128) void head_kernel(
    const float* __restrict__ gmax, const float* __restrict__ gsum, const float* __restrict__ gcnt,
    const float* __restrict__ h1w, const float* __restrict__ h1b,
    const float* __restrict__ bn1g, const float* __restrict__ bn1b,
    const float* __restrict__ bn1m, const float* __restrict__ bn1v,
    const float* __restrict__ h2w, const float* __restrict__ h2b,
    const float* __restrict__ bn2g, const float* __restrict__ bn2b,
    const float* __restrict__ bn2m, const float* __restrict__ bn2v,
    const float* __restrict__ h3w, const float* __restrict__ h3b,
    float* __restrict__ out)
{
    __shared__ float feat[2 * H2];
    __shared__ float z1s[H2];
    __shared__ float z2s[H2 / 2];
    int b = blockIdx.x, tid = threadIdx.x;
    float cnt = fmaxf(gcnt[b], 1.0f);
    if (tid < H2) feat[tid] = gmax[b * H2 + tid];
    else          feat[tid] = gsum[b * H2 + (tid - H2)] / cnt;
    __syncthreads();
    if (tid < H2) {
        float acc = h1b[tid];
#pragma unroll
        for (int j = 0; j < 2 * H2; ++j) acc += feat[j] * h1w[j * H2 + tid];
        acc = (acc - bn1m[tid]) * rsqrtf(bn1v[tid] + BN_EPS) * bn1g[tid] + bn1b[tid];
        z1s[tid] = fmaxf(acc, 0.0f);
    }
    __syncthreads();
    if (tid < H2 / 2) {
        float acc = h2b[tid];
#pragma unroll
        for (int j = 0; j < H2; ++j) acc += z1s[j] * h2w[j * (H2 / 2) + tid];
        acc = (acc - bn2m[tid]) * rsqrtf(bn2v[tid] + BN_EPS) * bn2g[tid] + bn2b[tid];
        z2s[tid] = fmaxf(acc, 0.0f);
    }
    __syncthreads();
    if (tid == 0) {
        float acc = h3b[0];
#pragma unroll
        for (int j = 0; j < H2 / 2; ++j) acc += z2s[j] * h3w[j];
        out[b] = acc;
    }
}

// ---------------------------------------------------------------- launch
extern "C" void kernel_launch(void* const* d_in, const int* in_sizes, int n_in,
                              void* d_out, int out_size, void* d_ws, size_t ws_size,
                              hipStream_t stream)
{
    const float* x         = (const float*)d_in[0];
    const int*   ei        = (const int*)d_in[1];
    const float* edge_attr = (const float*)d_in[2];
    const int*   batch     = (const int*)d_in[3];
    const float* e1_w1 = (const float*)d_in[4];
    const float* e1_b1 = (const float*)d_in[5];
    const float* e1_w2 = (const float*)d_in[6];
    const float* e1_b2 = (const float*)d_in[7];
    const float* root1 = (const float*)d_in[8];
    const float* bias1 = (const float*)d_in[9];
    const float* e2_w1 = (const float*)d_in[10];
    const float* e2_b1 = (const float*)d_in[11];
    const float* e2_w2 = (const float*)d_in[12];
    const float* e2_b2 = (const float*)d_in[13];
    const float* root2 = (const float*)d_in[14];
    const float* bias2 = (const float*)d_in[15];
    const float* h1w = (const float*)d_in[16];
    const float* h1b = (const float*)d_in[17];
    const float* bn1g = (const float*)d_in[18];
    const float* bn1b = (const float*)d_in[19];
    const float* bn1m = (const float*)d_in[20];
    const float* bn1v = (const float*)d_in[21];
    const float* h2w = (const float*)d_in[22];
    const float* h2b = (const float*)d_in[23];
    const float* bn2g = (const float*)d_in[24];
    const float* bn2b = (const float*)d_in[25];
    const float* bn2m = (const float*)d_in[26];
    const float* bn2v = (const float*)d_in[27];
    const float* h3w = (const float*)d_in[28];
    const float* h3b = (const float*)d_in[29];
    float* out = (float*)d_out;

    float* ws = (float*)d_ws;
    float* hedge = ws;                                   // E*EHID
    float* out1  = hedge + (size_t)N_EDGES * EHID;       // N*H1
    float* agg1  = out1 + (size_t)N_NODES * H1;          // N*H1
    float* agg2  = agg1 + (size_t)N_NODES * H1;          // N*H2
    float* h2o   = agg2 + (size_t)N_NODES * H2;          // N*H2
    float* gmaxb = h2o + (size_t)N_NODES * H2;           // NGRAPH*H2
    float* gsumb = gmaxb + NGRAPH * H2;                  // NGRAPH*H2
    float* gcntb = gsumb + NGRAPH * H2;                  // NGRAPH (+pad)
    unsigned short* w2t1 = (unsigned short*)(gcntb + 256);        // H1*KTOT bf16
    unsigned short* w2t2 = w2t1 + (size_t)H1 * KTOT;              // H2*KTOT bf16

    const int* srcp = ei;
    const int* dstp = ei + N_EDGES;

    init_kernel<<<2048, 256, 0, stream>>>(agg1, agg2, gmaxb, gsumb, gcntb);
    {
        int total = (H1 + H2) * KTOT;
        prep_w2t_kernel<<<(total + 255) / 256, 256, 0, stream>>>(e1_w2, e1_b2, e2_w2, e2_b2, w2t1, w2t2);
    }

    const int msg_blocks = (N_EDGES + 63) / 64;

    // layer 1
    edge_hidden_kernel<<<(N_EDGES + 255) / 256, 256, 0, stream>>>(edge_attr, e1_w1, e1_b1, hedge);
    msg_mfma_kernel<H1><<<msg_blocks, 256, 0, stream>>>(x, hedge, srcp, dstp, w2t1, agg1);
    node_update_kernel<H1, true><<<N_NODES / 8, 256, 0, stream>>>(x, root1, agg1, bias1, out1);

    // layer 2
    edge_hidden_kernel<<<(N_EDGES + 255) / 256, 256, 0, stream>>>(edge_attr, e2_w1, e2_b1, hedge);
    msg_mfma_kernel<H2><<<msg_blocks, 256, 0, stream>>>(out1, hedge, srcp, dstp, w2t2, agg2);
    node_update_kernel<H2, false><<<N_NODES / 4, 256, 0, stream>>>(out1, root2, agg2, bias2, h2o);

    // pooling + head
    pool_scan_kernel<<<(N_NODES + 63) / 64, 256, 0, stream>>>(h2o, batch, gmaxb, gsumb, gcntb);
    head_kernel<<<NGRAPH, 128, 0, stream>>>(gmaxb, gsumb, gcntb,
                                            h1w, h1b, bn1g, bn1b, bn1m, bn1v,
                                            h2w, h2b, bn2g, bn2b, bn2m, bn2v,
                                            h3w, h3b, out);
}

// Round 3
// 122.152 us; speedup vs baseline: 5.4512x; 1.2431x over previous
//
#include <hip/hip_runtime.h>
#include <hip/hip_fp16.h>

#define N_NODES 50000
#define N_EDGES 100000
#define EDGE_DIM 8
#define EHID 32
#define DIN 32
#define H1 32
#define H2 64
#define NGRAPH 256
#define BN_EPS 1e-5f
#define KTOT 1056   // EHID*DIN + DIN (b2 rows appended as slice 32)

#define EH_BLOCKS  ((N_EDGES + 255) / 256)        // 391
#define PREP_TOTAL ((H1 + H2) * KTOT)             // 101376
#define PREP_BLOCKS (PREP_TOTAL / 256)            // 396 exact
#define INIT_BLOCKS 253
#define MSG_BLOCKS 512

typedef __attribute__((ext_vector_type(8))) _Float16 f16x8;
typedef __attribute__((ext_vector_type(4))) float f32x4;

// ---------------------------------------------------------------- utilities
__device__ inline void atomicMaxF(float* addr, float v) {
    if (v >= 0.0f) atomicMax((int*)addr, __float_as_int(v));
    else           atomicMin((unsigned int*)addr, __float_as_uint(v));
}

// pack two floats to packed-f16 (u32), round-toward-zero (v_cvt_pkrtz_f16_f32)
__device__ inline unsigned int pk_f16(float a, float b) {
    unsigned int r;
    asm("v_cvt_pkrtz_f16_f32 %0, %1, %2" : "=v"(r) : "v"(a), "v"(b));
    return r;
}

// ---------------------------------------------------------------- prologue: edge MLP (both layers, packed-f16 out) + w2->f16 transpose + zero-init
__global__ __launch_bounds__(256) void prologue_kernel(
    const float* __restrict__ edge_attr,
    const float* __restrict__ e1w1, const float* __restrict__ e1b1,
    const float* __restrict__ e2w1, const float* __restrict__ e2b1,
    const float* __restrict__ e1w2, const float* __restrict__ e1b2,
    const float* __restrict__ e2w2, const float* __restrict__ e2b2,
    unsigned int* __restrict__ hpk1, unsigned int* __restrict__ hpk2,
    unsigned short* __restrict__ w2h1, unsigned short* __restrict__ w2h2,
    float* __restrict__ agg1, float* __restrict__ agg2,
    float* __restrict__ gmax, float* __restrict__ gsum, float* __restrict__ gcnt)
{
    int bid = blockIdx.x, tid = threadIdx.x;
    if (bid < EH_BLOCKS) {
        // ---- edge MLP, both layers, h stored as duplicated-half2 u32
        __shared__ float s_w[2][EDGE_DIM * EHID];
        __shared__ float s_b[2][EHID];
        if (tid < EDGE_DIM * EHID) { s_w[0][tid] = e1w1[tid]; s_w[1][tid] = e2w1[tid]; }
        if (tid < EHID) { s_b[0][tid] = e1b1[tid]; s_b[1][tid] = e2b1[tid]; }
        __syncthreads();
        int e = bid * 256 + tid;
        if (e >= N_EDGES) return;
        const float4* eap = reinterpret_cast<const float4*>(edge_attr + (size_t)e * EDGE_DIM);
        float4 v0 = eap[0], v1 = eap[1];
        float ea[EDGE_DIM] = {v0.x, v0.y, v0.z, v0.w, v1.x, v1.y, v1.z, v1.w};
#pragma unroll
        for (int L = 0; L < 2; ++L) {
            unsigned int* hp = (L == 0 ? hpk1 : hpk2) + (size_t)e * EHID;
#pragma unroll
            for (int k4 = 0; k4 < EHID; k4 += 4) {
                unsigned int t[4];
#pragma unroll
                for (int q = 0; q < 4; ++q) {
                    int k = k4 + q;
                    float acc = s_b[L][k];
#pragma unroll
                    for (int j = 0; j < EDGE_DIM; ++j) acc += ea[j] * s_w[L][j * EHID + k];
                    acc = fmaxf(acc, 0.0f);
                    t[q] = pk_f16(acc, acc);
                }
                uint4 r; r.x = t[0]; r.y = t[1]; r.z = t[2]; r.w = t[3];
                *reinterpret_cast<uint4*>(hp + k4) = r;
            }
        }
    } else if (bid < EH_BLOCKS + PREP_BLOCKS) {
        // ---- w2 + b2 -> f16 [DOUT][KTOT]
        int idx = (bid - EH_BLOCKS) * 256 + tid;
        const int n1 = H1 * KTOT;
        if (idx < n1) {
            int o = idx / KTOT, k = idx % KTOT;
            float v = (k < EHID * DIN) ? e1w2[(k >> 5) * (DIN * H1) + (k & 31) * H1 + o]
                                       : e1b2[(k - EHID * DIN) * H1 + o];
            w2h1[idx] = __half_as_ushort(__float2half(v));
        } else {
            int j = idx - n1;
            int o = j / KTOT, k = j % KTOT;
            float v = (k < EHID * DIN) ? e2w2[(k >> 5) * (DIN * H2) + (k & 31) * H2 + o]
                                       : e2b2[(k - EHID * DIN) * H2 + o];
            w2h2[j] = __half_as_ushort(__float2half(v));
        }
    } else {
        // ---- zero init
        int lb = bid - EH_BLOCKS - PREP_BLOCKS;
        int stride = INIT_BLOCKS * 256;
        int i0 = lb * 256 + tid;
        for (int i = i0; i < N_NODES * H1; i += stride) agg1[i] = 0.0f;
        for (int i = i0; i < N_NODES * H2; i += stride) agg2[i] = 0.0f;
        for (int i = i0; i < NGRAPH * H2; i += stride) { gmax[i] = __int_as_float(0xff800000); gsum[i] = 0.0f; }
        for (int i = i0; i < NGRAPH; i += stride) gcnt[i] = 0.0f;
    }
}

// ---------------------------------------------------------------- MFMA message + scatter, B-in-registers, zero barriers
// msg[E,DOUT] = U[E,KTOT] @ Bmat[KTOT,DOUT]; U[e, kk*32+i] = h[e,kk]*g[e,i] (kk=32 -> h=1 -> b2 term)
template <int DOUT>
__global__ __launch_bounds__(256, 2) void msg_v3_kernel(
    const float* __restrict__ gsrc,          // [N, 32]
    const unsigned int* __restrict__ hpk,    // [E, 32] duplicated-half2
    const int* __restrict__ src, const int* __restrict__ dst,
    const unsigned short* __restrict__ w2h,  // f16 [DOUT][KTOT]
    float* __restrict__ agg)                 // [N, DOUT]
{
    constexpr int NT = DOUT / 16;            // o-tiles
    __shared__ unsigned int hlds[4][16][33]; // wave-private h tiles, stride 33 (conflict-free)

    const int tid = threadIdx.x;
    const int wave = tid >> 6;
    const int lane = tid & 63;
    const int col = lane & 15;               // A-row (edge) index == B-col (o) index
    const int kq = lane >> 4;

    const int wg = blockIdx.x * 4 + wave;
    const int ot = wg & (NT - 1);
    const int stream = wg / NT;
    const int nstreams = (MSG_BLOCKS * 4) / NT;

    // B fragments for all 33 k-slices, held in VGPRs (132)
    f16x8 B[33];
    {
        const unsigned short* bp = w2h + (size_t)(ot * 16 + col) * KTOT + kq * 8;
#pragma unroll
        for (int kk = 0; kk < 33; ++kk)
            B[kk] = *reinterpret_cast<const f16x8*>(bp + kk * 32);
    }

    const int nchunks = N_EDGES / 16;        // 6250, exact
    for (int c = stream; c < nchunks; c += nstreams) {
        const int e0 = c * 16;
        const int myE = e0 + col;
        const int s = src[myE];

        // g -> packed f16 (4 u32 = 8 halves), also the b2-slice A-fragment
        float4 ga = *reinterpret_cast<const float4*>(gsrc + (size_t)s * DIN + kq * 8);
        float4 gb = *reinterpret_cast<const float4*>(gsrc + (size_t)s * DIN + kq * 8 + 4);
        union { unsigned int u[4]; f16x8 v; } gf;
        gf.u[0] = pk_f16(ga.x, ga.y);
        gf.u[1] = pk_f16(ga.z, ga.w);
        gf.u[2] = pk_f16(gb.x, gb.y);
        gf.u[3] = pk_f16(gb.z, gb.w);

        // stage this wave's 16x32 h tile (already duplicated-half2)
        const uint4* hp = reinterpret_cast<const uint4*>(hpk + (size_t)myE * EHID + kq * 8);
        uint4 h0 = hp[0], h1v = hp[1];
        *reinterpret_cast<uint4*>(&hlds[wave][col][kq * 8]) = h0;
        *reinterpret_cast<uint4*>(&hlds[wave][col][kq * 8 + 4]) = h1v;
        asm volatile("s_waitcnt lgkmcnt(0)" ::: "memory");  // wave-private visibility, no barrier

        f32x4 acc = (f32x4){0.f, 0.f, 0.f, 0.f};
#pragma unroll
        for (int kk = 0; kk < 32; ++kk) {
            unsigned int hh = hlds[wave][col][kk];          // broadcast read
            union { unsigned int u[4]; f16x8 v; } af;
            asm("v_pk_mul_f16 %0, %1, %2" : "=v"(af.u[0]) : "v"(hh), "v"(gf.u[0]));
            asm("v_pk_mul_f16 %0, %1, %2" : "=v"(af.u[1]) : "v"(hh), "v"(gf.u[1]));
            asm("v_pk_mul_f16 %0, %1, %2" : "=v"(af.u[2]) : "v"(hh), "v"(gf.u[2]));
            asm("v_pk_mul_f16 %0, %1, %2" : "=v"(af.u[3]) : "v"(hh), "v"(gf.u[3]));
            acc = __builtin_amdgcn_mfma_f32_16x16x32_f16(af.v, B[kk], acc, 0, 0, 0);
        }
        // b2 slice: h == 1 -> A = f16(g)
        acc = __builtin_amdgcn_mfma_f32_16x16x32_f16(gf.v, B[32], acc, 0, 0, 0);

        // scatter: C row = edge (kq*4+r), col = o (ot*16+col)
        int4 dd = *reinterpret_cast<const int4*>(dst + e0 + kq * 4);
        const int dv[4] = {dd.x, dd.y, dd.z, dd.w};
#pragma unroll
        for (int r = 0; r < 4; ++r)
            atomicAdd(&agg[(size_t)dv[r] * DOUT + ot * 16 + col], acc[r]);
    }
}

// ---------------------------------------------------------------- node update: out = act(in@root + agg + bias), grid-strided
template <int DOUTN, bool RELU>
__global__ __launch_bounds__(256) void node_update_kernel(
    const float* __restrict__ in, const float* __restrict__ root,
    const float* __restrict__ agg, const float* __restrict__ bias,
    float* __restrict__ out)
{
    constexpr int NPB = 256 / DOUTN;
    __shared__ float roots[DIN * DOUTN];
    __shared__ float ins[NPB][DIN + 1];
    int tid = threadIdx.x;
    for (int idx = tid; idx < DIN * DOUTN; idx += 256) roots[idx] = root[idx];
    int o = tid % DOUTN, nl = tid / DOUTN;
    float bo = bias[o];
    const int nchunks = (N_NODES + NPB - 1) / NPB;
    for (int c = blockIdx.x; c < nchunks; c += gridDim.x) {
        int nBase = c * NPB;
        __syncthreads();
        for (int idx = tid; idx < NPB * DIN; idx += 256) {
            int nn = nBase + idx / DIN;
            ins[idx / DIN][idx % DIN] = (nn < N_NODES) ? in[(size_t)nn * DIN + (idx % DIN)] : 0.0f;
        }
        __syncthreads();
        int n = nBase + nl;
        if (n < N_NODES) {
            float t = agg[(size_t)n * DOUTN + o] + bo;
#pragma unroll
            for (int i = 0; i < DIN; ++i) t += ins[nl][i] * roots[i * DOUTN + o];
            if (RELU) t = fmaxf(t, 0.0f);
            out[(size_t)n * DOUTN + o] = t;
        }
    }
}

// ---------------------------------------------------------------- pooling: sorted-run scan
__global__ __launch_bounds__(256) void pool_scan_kernel(
    const float* __restrict__ h, const int* __restrict__ batch,
    float* gmax, float* gsum, float* gcnt)
{
    __shared__ int s_batch[64];
    int tid = threadIdx.x;
    int base = blockIdx.x * 64;
    if (tid < 64) s_batch[tid] = (base + tid < N_NODES) ? batch[base + tid] : -1;
    __syncthreads();
    int o = tid & 63, r = tid >> 6;
    int curb = -1; float s = 0.f, m = __int_as_float(0xff800000); float c = 0.f;
#pragma unroll
    for (int j = 0; j < 16; ++j) {
        int n = base + r * 16 + j;
        if (n >= N_NODES) break;
        int b = s_batch[r * 16 + j];
        if (b != curb) {
            if (curb >= 0) {
                atomicAdd(&gsum[curb * H2 + o], s);
                atomicMaxF(&gmax[curb * H2 + o], m);
                if (o == 0) atomicAdd(&gcnt[curb], c);
            }
            curb = b; s = 0.f; m = __int_as_float(0xff800000); c = 0.f;
        }
        float v = h[(size_t)n * H2 + o];
        s += v; m = fmaxf(m, v); c += 1.f;
    }
    if (curb >= 0) {
        atomicAdd(&gsum[curb * H2 + o], s);
        atomicMaxF(&gmax[curb * H2 + o], m);
        if (o == 0) atomicAdd(&gcnt[curb], c);
    }
}

// ---------------------------------------------------------------- MLP head
__global__ __launch_bounds__(128) void head_kernel(
    const float* __restrict__ gmax, const float* __restrict__ gsum, const float* __restrict__ gcnt,
    const float* __restrict__ h1w, const float* __restrict__ h1b,
    const float* __restrict__ bn1g, const float* __restrict__ bn1b,
    const float* __restrict__ bn1m, const float* __restrict__ bn1v,
    const float* __restrict__ h2w, const float* __restrict__ h2b,
    const float* __restrict__ bn2g, const float* __restrict__ bn2b,
    const float* __restrict__ bn2m, const float* __restrict__ bn2v,
    const float* __restrict__ h3w, const float* __restrict__ h3b,
    float* __restrict__ out)
{
    __shared__ float feat[2 * H2];
    __shared__ float z1s[H2];
    __shared__ float z2s[H2 / 2];
    int b = blockIdx.x, tid = threadIdx.x;
    float cnt = fmaxf(gcnt[b], 1.0f);
    if (tid < H2) feat[tid] = gmax[b * H2 + tid];
    else          feat[tid] = gsum[b * H2 + (tid - H2)] / cnt;
    __syncthreads();
    if (tid < H2) {
        float acc = h1b[tid];
#pragma unroll
        for (int j = 0; j < 2 * H2; ++j) acc += feat[j] * h1w[j * H2 + tid];
        acc = (acc - bn1m[tid]) * rsqrtf(bn1v[tid] + BN_EPS) * bn1g[tid] + bn1b[tid];
        z1s[tid] = fmaxf(acc, 0.0f);
    }
    __syncthreads();
    if (tid < H2 / 2) {
        float acc = h2b[tid];
#pragma unroll
        for (int j = 0; j < H2; ++j) acc += z1s[j] * h2w[j * (H2 / 2) + tid];
        acc = (acc - bn2m[tid]) * rsqrtf(bn2v[tid] + BN_EPS) * bn2g[tid] + bn2b[tid];
        z2s[tid] = fmaxf(acc, 0.0f);
    }
    __syncthreads();
    if (tid == 0) {
        float acc = h3b[0];
#pragma unroll
        for (int j = 0; j < H2 / 2; ++j) acc += z2s[j] * h3w[j];
        out[b] = acc;
    }
}

// ---------------------------------------------------------------- launch
extern "C" void kernel_launch(void* const* d_in, const int* in_sizes, int n_in,
                              void* d_out, int out_size, void* d_ws, size_t ws_size,
                              hipStream_t stream)
{
    const float* x         = (const float*)d_in[0];
    const int*   ei        = (const int*)d_in[1];
    const float* edge_attr = (const float*)d_in[2];
    const int*   batch     = (const int*)d_in[3];
    const float* e1_w1 = (const float*)d_in[4];
    const float* e1_b1 = (const float*)d_in[5];
    const float* e1_w2 = (const float*)d_in[6];
    const float* e1_b2 = (const float*)d_in[7];
    const float* root1 = (const float*)d_in[8];
    const float* bias1 = (const float*)d_in[9];
    const float* e2_w1 = (const float*)d_in[10];
    const float* e2_b1 = (const float*)d_in[11];
    const float* e2_w2 = (const float*)d_in[12];
    const float* e2_b2 = (const float*)d_in[13];
    const float* root2 = (const float*)d_in[14];
    const float* bias2 = (const float*)d_in[15];
    const float* h1w = (const float*)d_in[16];
    const float* h1b = (const float*)d_in[17];
    const float* bn1g = (const float*)d_in[18];
    const float* bn1b = (const float*)d_in[19];
    const float* bn1m = (const float*)d_in[20];
    const float* bn1v = (const float*)d_in[21];
    const float* h2w = (const float*)d_in[22];
    const float* h2b = (const float*)d_in[23];
    const float* bn2g = (const float*)d_in[24];
    const float* bn2b = (const float*)d_in[25];
    const float* bn2m = (const float*)d_in[26];
    const float* bn2v = (const float*)d_in[27];
    const float* h3w = (const float*)d_in[28];
    const float* h3b = (const float*)d_in[29];
    float* out = (float*)d_out;

    float* ws = (float*)d_ws;
    unsigned int* hpk1 = (unsigned int*)ws;              // E*32 u32 (aliased as h2o later)
    unsigned int* hpk2 = hpk1 + (size_t)N_EDGES * EHID;  // E*32 u32
    float* out1  = (float*)(hpk2 + (size_t)N_EDGES * EHID); // N*H1
    float* agg1  = out1 + (size_t)N_NODES * H1;          // N*H1
    float* agg2  = agg1 + (size_t)N_NODES * H1;          // N*H2
    float* gmaxb = agg2 + (size_t)N_NODES * H2;          // NGRAPH*H2
    float* gsumb = gmaxb + NGRAPH * H2;                  // NGRAPH*H2
    float* gcntb = gsumb + NGRAPH * H2;                  // NGRAPH (+pad)
    unsigned short* w2h1 = (unsigned short*)(gcntb + 256);   // H1*KTOT f16
    unsigned short* w2h2 = w2h1 + (size_t)H1 * KTOT;         // H2*KTOT f16
    float* h2o = (float*)hpk1;                           // N*H2 f32, aliases hpk1 (dead after msg1)

    const int* srcp = ei;
    const int* dstp = ei + N_EDGES;

    prologue_kernel<<<EH_BLOCKS + PREP_BLOCKS + INIT_BLOCKS, 256, 0, stream>>>(
        edge_attr, e1_w1, e1_b1, e2_w1, e2_b1, e1_w2, e1_b2, e2_w2, e2_b2,
        hpk1, hpk2, w2h1, w2h2, agg1, agg2, gmaxb, gsumb, gcntb);

    msg_v3_kernel<H1><<<MSG_BLOCKS, 256, 0, stream>>>(x, hpk1, srcp, dstp, w2h1, agg1);
    node_update_kernel<H1, true><<<2048, 256, 0, stream>>>(x, root1, agg1, bias1, out1);

    msg_v3_kernel<H2><<<MSG_BLOCKS, 256, 0, stream>>>(out1, hpk2, srcp, dstp, w2h2, agg2);
    node_update_kernel<H2, false><<<2048, 256, 0, stream>>>(out1, root2, agg2, bias2, h2o);

    pool_scan_kernel<<<(N_NODES + 63) / 64, 256, 0, stream>>>(h2o, batch, gmaxb, gsumb, gcntb);
    head_kernel<<<NGRAPH, 128, 0, stream>>>(gmaxb, gsumb, gcntb,
                                            h1w, h1b, bn1g, bn1b, bn1m, bn1v,
                                            h2w, h2b, bn2g, bn2b, bn2m, bn2v,
                                            h3w, h3b, out);
}

// Round 4
// 116.864 us; speedup vs baseline: 5.6978x; 1.0452x over previous
//
#include <hip/hip_runtime.h>
#include <hip/hip_fp16.h>

#define N_NODES 50000
#define N_EDGES 100000
#define EDGE_DIM 8
#define EHID 32
#define DIN 32
#define H1 32
#define H2 64
#define NGRAPH 256
#define BN_EPS 1e-5f
#define KTOT 1056   // EHID*DIN + DIN (b2 rows appended as slice 32)

#define EH_BLOCKS  ((N_EDGES + 255) / 256)        // 391
#define PREP_TOTAL ((H1 + H2) * KTOT)             // 101376
#define PREP_BLOCKS (PREP_TOTAL / 256)            // 396 exact
#define INIT_BLOCKS 253
#define MSG_BLOCKS 512

typedef __attribute__((ext_vector_type(8))) _Float16 f16x8;
typedef __attribute__((ext_vector_type(4))) float f32x4;
typedef unsigned int uint32;

// ---------------------------------------------------------------- utilities
__device__ inline void atomicMaxF(float* addr, float v) {
    if (v >= 0.0f) atomicMax((int*)addr, __float_as_int(v));
    else           atomicMin((unsigned int*)addr, __float_as_uint(v));
}

__device__ inline uint32 pk_f16(float a, float b) {
    uint32 r;
    asm("v_cvt_pkrtz_f16_f32 %0, %1, %2" : "=v"(r) : "v"(a), "v"(b));
    return r;
}

union GF { uint32 u[4]; f16x8 v; };

__device__ inline f16x8 mul_h(uint32 h, const GF& g) {
    GF r;
    asm("v_pk_mul_f16 %0, %1, %2" : "=v"(r.u[0]) : "v"(h), "v"(g.u[0]));
    asm("v_pk_mul_f16 %0, %1, %2" : "=v"(r.u[1]) : "v"(h), "v"(g.u[1]));
    asm("v_pk_mul_f16 %0, %1, %2" : "=v"(r.u[2]) : "v"(h), "v"(g.u[2]));
    asm("v_pk_mul_f16 %0, %1, %2" : "=v"(r.u[3]) : "v"(h), "v"(g.u[3]));
    return r.v;
}

// ---------------------------------------------------------------- prologue: edge MLP + w2->f16 transpose + zero-init
__global__ __launch_bounds__(256) void prologue_kernel(
    const float* __restrict__ edge_attr,
    const float* __restrict__ e1w1, const float* __restrict__ e1b1,
    const float* __restrict__ e2w1, const float* __restrict__ e2b1,
    const float* __restrict__ e1w2, const float* __restrict__ e1b2,
    const float* __restrict__ e2w2, const float* __restrict__ e2b2,
    uint32* __restrict__ hpk1, uint32* __restrict__ hpk2,
    unsigned short* __restrict__ w2h1, unsigned short* __restrict__ w2h2,
    float* __restrict__ agg1, float* __restrict__ agg2,
    float* __restrict__ gmax, float* __restrict__ gsum, float* __restrict__ gcnt)
{
    int bid = blockIdx.x, tid = threadIdx.x;
    if (bid < EH_BLOCKS) {
        __shared__ float s_w[2][EDGE_DIM * EHID];
        __shared__ float s_b[2][EHID];
        if (tid < EDGE_DIM * EHID) { s_w[0][tid] = e1w1[tid]; s_w[1][tid] = e2w1[tid]; }
        if (tid < EHID) { s_b[0][tid] = e1b1[tid]; s_b[1][tid] = e2b1[tid]; }
        __syncthreads();
        int e = bid * 256 + tid;
        if (e >= N_EDGES) return;
        const float4* eap = reinterpret_cast<const float4*>(edge_attr + (size_t)e * EDGE_DIM);
        float4 v0 = eap[0], v1 = eap[1];
        float ea[EDGE_DIM] = {v0.x, v0.y, v0.z, v0.w, v1.x, v1.y, v1.z, v1.w};
#pragma unroll
        for (int L = 0; L < 2; ++L) {
            uint32* hp = (L == 0 ? hpk1 : hpk2) + (size_t)e * EHID;
#pragma unroll
            for (int k4 = 0; k4 < EHID; k4 += 4) {
                uint32 t[4];
#pragma unroll
                for (int q = 0; q < 4; ++q) {
                    int k = k4 + q;
                    float acc = s_b[L][k];
#pragma unroll
                    for (int j = 0; j < EDGE_DIM; ++j) acc += ea[j] * s_w[L][j * EHID + k];
                    acc = fmaxf(acc, 0.0f);
                    t[q] = pk_f16(acc, acc);
                }
                uint4 r; r.x = t[0]; r.y = t[1]; r.z = t[2]; r.w = t[3];
                *reinterpret_cast<uint4*>(hp + k4) = r;
            }
        }
    } else if (bid < EH_BLOCKS + PREP_BLOCKS) {
        int idx = (bid - EH_BLOCKS) * 256 + tid;
        const int n1 = H1 * KTOT;
        if (idx < n1) {
            int o = idx / KTOT, k = idx % KTOT;
            float v = (k < EHID * DIN) ? e1w2[(k >> 5) * (DIN * H1) + (k & 31) * H1 + o]
                                       : e1b2[(k - EHID * DIN) * H1 + o];
            w2h1[idx] = __half_as_ushort(__float2half(v));
        } else {
            int j = idx - n1;
            int o = j / KTOT, k = j % KTOT;
            float v = (k < EHID * DIN) ? e2w2[(k >> 5) * (DIN * H2) + (k & 31) * H2 + o]
                                       : e2b2[(k - EHID * DIN) * H2 + o];
            w2h2[j] = __half_as_ushort(__float2half(v));
        }
    } else {
        int lb = bid - EH_BLOCKS - PREP_BLOCKS;
        int stride = INIT_BLOCKS * 256;
        int i0 = lb * 256 + tid;
        for (int i = i0; i < N_NODES * H1; i += stride) agg1[i] = 0.0f;
        for (int i = i0; i < N_NODES * H2; i += stride) agg2[i] = 0.0f;
        for (int i = i0; i < NGRAPH * H2; i += stride) { gmax[i] = __int_as_float(0xff800000); gsum[i] = 0.0f; }
        for (int i = i0; i < NGRAPH; i += stride) gcnt[i] = 0.0f;
    }
}

// ---------------------------------------------------------------- MFMA message + scatter, v4:
// B-in-registers, zero barriers, 32 edges/iter (2 independent MFMA chains), 2-deep pipelined loads.
template <int DOUT>
__global__ __launch_bounds__(256, 2) void msg_v4_kernel(
    const float* __restrict__ gsrc,          // [N, 32]
    const uint32* __restrict__ hpk,          // [E, 32] duplicated-half2
    const int* __restrict__ src, const int* __restrict__ dst,
    const unsigned short* __restrict__ w2h,  // f16 [DOUT][KTOT]
    float* __restrict__ agg)                 // [N, DOUT]
{
    constexpr int NT = DOUT / 16;
    __shared__ __align__(16) uint32 hlds[4][2][32][36];  // [wave][buf][edge-row][kk], stride 36

    const int tid = threadIdx.x;
    const int wave = tid >> 6;
    const int lane = tid & 63;
    const int col = lane & 15;
    const int kq = lane >> 4;

    const int w = blockIdx.x * 4 + wave;
    const int ot = w % NT;
    int it = w / NT;
    const int strideIt = (MSG_BLOCKS * 4) / NT;
    const int NIT = N_EDGES / 32;            // 3125 exact

    // B fragments for all 33 k-slices (132 VGPRs)
    f16x8 B[33];
    {
        const unsigned short* bp = w2h + (size_t)(ot * 16 + col) * KTOT + kq * 8;
#pragma unroll
        for (int kk = 0; kk < 33; ++kk)
            B[kk] = *reinterpret_cast<const f16x8*>(bp + kk * 32);
    }
    if (it >= NIT) return;

    int buf = 0;

    // ---------------- pipeline prologue: fully stage iter `it`
    int e0 = it * 32;
    int sA = src[e0 + col], sB = src[e0 + 16 + col];
    float4 gA0 = *reinterpret_cast<const float4*>(gsrc + (size_t)sA * DIN + kq * 8);
    float4 gA1 = *reinterpret_cast<const float4*>(gsrc + (size_t)sA * DIN + kq * 8 + 4);
    float4 gB0 = *reinterpret_cast<const float4*>(gsrc + (size_t)sB * DIN + kq * 8);
    float4 gB1 = *reinterpret_cast<const float4*>(gsrc + (size_t)sB * DIN + kq * 8 + 4);
    uint4 hA0 = *reinterpret_cast<const uint4*>(hpk + (size_t)(e0 + col) * EHID + kq * 8);
    uint4 hA1 = *reinterpret_cast<const uint4*>(hpk + (size_t)(e0 + col) * EHID + kq * 8 + 4);
    uint4 hB0 = *reinterpret_cast<const uint4*>(hpk + (size_t)(e0 + 16 + col) * EHID + kq * 8);
    uint4 hB1 = *reinterpret_cast<const uint4*>(hpk + (size_t)(e0 + 16 + col) * EHID + kq * 8 + 4);
    int4 ddA = *reinterpret_cast<const int4*>(dst + e0 + kq * 4);
    int4 ddB = *reinterpret_cast<const int4*>(dst + e0 + 16 + kq * 4);

    int it1 = it + strideIt;
    int s1A = 0, s1B = 0;
    if (it1 < NIT) { s1A = src[it1 * 32 + col]; s1B = src[it1 * 32 + 16 + col]; }

    GF gfA, gfB;
    gfA.u[0] = pk_f16(gA0.x, gA0.y); gfA.u[1] = pk_f16(gA0.z, gA0.w);
    gfA.u[2] = pk_f16(gA1.x, gA1.y); gfA.u[3] = pk_f16(gA1.z, gA1.w);
    gfB.u[0] = pk_f16(gB0.x, gB0.y); gfB.u[1] = pk_f16(gB0.z, gB0.w);
    gfB.u[2] = pk_f16(gB1.x, gB1.y); gfB.u[3] = pk_f16(gB1.z, gB1.w);
    *reinterpret_cast<uint4*>(&hlds[wave][0][col][kq * 8])          = hA0;
    *reinterpret_cast<uint4*>(&hlds[wave][0][col][kq * 8 + 4])      = hA1;
    *reinterpret_cast<uint4*>(&hlds[wave][0][16 + col][kq * 8])     = hB0;
    *reinterpret_cast<uint4*>(&hlds[wave][0][16 + col][kq * 8 + 4]) = hB1;

    for (;;) {
        // issue src 2 iterations ahead
        int it2 = it1 + strideIt;
        int s2A = 0, s2B = 0;
        if (it2 < NIT) { s2A = src[it2 * 32 + col]; s2B = src[it2 * 32 + 16 + col]; }

        // issue g/h/dst for next iteration (src landed one full iteration ago)
        const bool nv = (it1 < NIT);
        float4 ngA0, ngA1, ngB0, ngB1;
        uint4 nhA0, nhA1, nhB0, nhB1;
        int4 nddA, nddB;
        if (nv) {
            int ne0 = it1 * 32;
            ngA0 = *reinterpret_cast<const float4*>(gsrc + (size_t)s1A * DIN + kq * 8);
            ngA1 = *reinterpret_cast<const float4*>(gsrc + (size_t)s1A * DIN + kq * 8 + 4);
            ngB0 = *reinterpret_cast<const float4*>(gsrc + (size_t)s1B * DIN + kq * 8);
            ngB1 = *reinterpret_cast<const float4*>(gsrc + (size_t)s1B * DIN + kq * 8 + 4);
            nhA0 = *reinterpret_cast<const uint4*>(hpk + (size_t)(ne0 + col) * EHID + kq * 8);
            nhA1 = *reinterpret_cast<const uint4*>(hpk + (size_t)(ne0 + col) * EHID + kq * 8 + 4);
            nhB0 = *reinterpret_cast<const uint4*>(hpk + (size_t)(ne0 + 16 + col) * EHID + kq * 8);
            nhB1 = *reinterpret_cast<const uint4*>(hpk + (size_t)(ne0 + 16 + col) * EHID + kq * 8 + 4);
            nddA = *reinterpret_cast<const int4*>(dst + ne0 + kq * 4);
            nddB = *reinterpret_cast<const int4*>(dst + ne0 + 16 + kq * 4);
        }

        // ---------------- MFMA on current iteration (two independent chains)
        f32x4 accA = (f32x4){0.f, 0.f, 0.f, 0.f};
        f32x4 accB = (f32x4){0.f, 0.f, 0.f, 0.f};
#pragma unroll
        for (int t = 0; t < 8; ++t) {
            uint4 ha = *reinterpret_cast<const uint4*>(&hlds[wave][buf][col][t * 4]);
            uint4 hb = *reinterpret_cast<const uint4*>(&hlds[wave][buf][16 + col][t * 4]);
            accA = __builtin_amdgcn_mfma_f32_16x16x32_f16(mul_h(ha.x, gfA), B[t * 4 + 0], accA, 0, 0, 0);
            accB = __builtin_amdgcn_mfma_f32_16x16x32_f16(mul_h(hb.x, gfB), B[t * 4 + 0], accB, 0, 0, 0);
            accA = __builtin_amdgcn_mfma_f32_16x16x32_f16(mul_h(ha.y, gfA), B[t * 4 + 1], accA, 0, 0, 0);
            accB = __builtin_amdgcn_mfma_f32_16x16x32_f16(mul_h(hb.y, gfB), B[t * 4 + 1], accB, 0, 0, 0);
            accA = __builtin_amdgcn_mfma_f32_16x16x32_f16(mul_h(ha.z, gfA), B[t * 4 + 2], accA, 0, 0, 0);
            accB = __builtin_amdgcn_mfma_f32_16x16x32_f16(mul_h(hb.z, gfB), B[t * 4 + 2], accB, 0, 0, 0);
            accA = __builtin_amdgcn_mfma_f32_16x16x32_f16(mul_h(ha.w, gfA), B[t * 4 + 3], accA, 0, 0, 0);
            accB = __builtin_amdgcn_mfma_f32_16x16x32_f16(mul_h(hb.w, gfB), B[t * 4 + 3], accB, 0, 0, 0);
        }
        // b2 slice (h == 1): A = f16(g)
        accA = __builtin_amdgcn_mfma_f32_16x16x32_f16(gfA.v, B[32], accA, 0, 0, 0);
        accB = __builtin_amdgcn_mfma_f32_16x16x32_f16(gfB.v, B[32], accB, 0, 0, 0);

        // ---------------- scatter current
        atomicAdd(&agg[(size_t)ddA.x * DOUT + ot * 16 + col], accA[0]);
        atomicAdd(&agg[(size_t)ddA.y * DOUT + ot * 16 + col], accA[1]);
        atomicAdd(&agg[(size_t)ddA.z * DOUT + ot * 16 + col], accA[2]);
        atomicAdd(&agg[(size_t)ddA.w * DOUT + ot * 16 + col], accA[3]);
        atomicAdd(&agg[(size_t)ddB.x * DOUT + ot * 16 + col], accB[0]);
        atomicAdd(&agg[(size_t)ddB.y * DOUT + ot * 16 + col], accB[1]);
        atomicAdd(&agg[(size_t)ddB.z * DOUT + ot * 16 + col], accB[2]);
        atomicAdd(&agg[(size_t)ddB.w * DOUT + ot * 16 + col], accB[3]);

        if (!nv) break;

        // ---------------- stage next iteration
        buf ^= 1;
        *reinterpret_cast<uint4*>(&hlds[wave][buf][col][kq * 8])          = nhA0;
        *reinterpret_cast<uint4*>(&hlds[wave][buf][col][kq * 8 + 4])      = nhA1;
        *reinterpret_cast<uint4*>(&hlds[wave][buf][16 + col][kq * 8])     = nhB0;
        *reinterpret_cast<uint4*>(&hlds[wave][buf][16 + col][kq * 8 + 4]) = nhB1;
        gfA.u[0] = pk_f16(ngA0.x, ngA0.y); gfA.u[1] = pk_f16(ngA0.z, ngA0.w);
        gfA.u[2] = pk_f16(ngA1.x, ngA1.y); gfA.u[3] = pk_f16(ngA1.z, ngA1.w);
        gfB.u[0] = pk_f16(ngB0.x, ngB0.y); gfB.u[1] = pk_f16(ngB0.z, ngB0.w);
        gfB.u[2] = pk_f16(ngB1.x, ngB1.y); gfB.u[3] = pk_f16(ngB1.z, ngB1.w);
        ddA = nddA; ddB = nddB;
        s1A = s2A; s1B = s2B;
        it = it1; it1 = it2;
    }
}

// ---------------------------------------------------------------- node update: out = act(in@root + agg + bias)
template <int DOUTN, bool RELU>
__global__ __launch_bounds__(256) void node_update_kernel(
    const float* __restrict__ in, const float* __restrict__ root,
    const float* __restrict__ agg, const float* __restrict__ bias,
    float* __restrict__ out)
{
    constexpr int NPB = 256 / DOUTN;
    __shared__ float roots[DIN * DOUTN];
    __shared__ float ins[NPB][DIN + 1];
    int tid = threadIdx.x;
    for (int idx = tid; idx < DIN * DOUTN; idx += 256) roots[idx] = root[idx];
    int o = tid % DOUTN, nl = tid / DOUTN;
    float bo = bias[o];
    const int nchunks = (N_NODES + NPB - 1) / NPB;
    for (int c = blockIdx.x; c < nchunks; c += gridDim.x) {
        int nBase = c * NPB;
        __syncthreads();
        for (int idx = tid; idx < NPB * DIN; idx += 256) {
            int nn = nBase + idx / DIN;
            ins[idx / DIN][idx % DIN] = (nn < N_NODES) ? in[(size_t)nn * DIN + (idx % DIN)] : 0.0f;
        }
        __syncthreads();
        int n = nBase + nl;
        if (n < N_NODES) {
            float t = agg[(size_t)n * DOUTN + o] + bo;
#pragma unroll
            for (int i = 0; i < DIN; ++i) t += ins[nl][i] * roots[i * DOUTN + o];
            if (RELU) t = fmaxf(t, 0.0f);
            out[(size_t)n * DOUTN + o] = t;
        }
    }
}

// ---------------------------------------------------------------- pooling: sorted-run scan
__global__ __launch_bounds__(256) void pool_scan_kernel(
    const float* __restrict__ h, const int* __restrict__ batch,
    float* gmax, float* gsum, float* gcnt)
{
    __shared__ int s_batch[64];
    int tid = threadIdx.x;
    int base = blockIdx.x * 64;
    if (tid < 64) s_batch[tid] = (base + tid < N_NODES) ? batch[base + tid] : -1;
    __syncthreads();
    int o = tid & 63, r = tid >> 6;
    int curb = -1; float s = 0.f, m = __int_as_float(0xff800000); float c = 0.f;
#pragma unroll
    for (int j = 0; j < 16; ++j) {
        int n = base + r * 16 + j;
        if (n >= N_NODES) break;
        int b = s_batch[r * 16 + j];
        if (b != curb) {
            if (curb >= 0) {
                atomicAdd(&gsum[curb * H2 + o], s);
                atomicMaxF(&gmax[curb * H2 + o], m);
                if (o == 0) atomicAdd(&gcnt[curb], c);
            }
            curb = b; s = 0.f; m = __int_as_float(0xff800000); c = 0.f;
        }
        float v = h[(size_t)n * H2 + o];
        s += v; m = fmaxf(m, v); c += 1.f;
    }
    if (curb >= 0) {
        atomicAdd(&gsum[curb * H2 + o], s);
        atomicMaxF(&gmax[curb * H2 + o], m);
        if (o == 0) atomicAdd(&gcnt[curb], c);
    }
}

// ---------------------------------------------------------------- MLP head
__global__ __launch_bounds__(128) void head_kernel(
    const float* __restrict__ gmax, const float* __restrict__ gsum, const float* __restrict__ gcnt,
    const float* __restrict__ h1w, const float* __restrict__ h1b,
    const float* __restrict__ bn1g, const float* __restrict__ bn1b,
    const float* __restrict__ bn1m, const float* __restrict__ bn1v,
    const float* __restrict__ h2w, const float* __restrict__ h2b,
    const float* __restrict__ bn2g, const float* __restrict__ bn2b,
    const float* __restrict__ bn2m, const float* __restrict__ bn2v,
    const float* __restrict__ h3w, const float* __restrict__ h3b,
    float* __restrict__ out)
{
    __shared__ float feat[2 * H2];
    __shared__ float z1s[H2];
    __shared__ float z2s[H2 / 2];
    int b = blockIdx.x, tid = threadIdx.x;
    float cnt = fmaxf(gcnt[b], 1.0f);
    if (tid < H2) feat[tid] = gmax[b * H2 + tid];
    else          feat[tid] = gsum[b * H2 + (tid - H2)] / cnt;
    __syncthreads();
    if (tid < H2) {
        float acc = h1b[tid];
#pragma unroll
        for (int j = 0; j < 2 * H2; ++j) acc += feat[j] * h1w[j * H2 + tid];
        acc = (acc - bn1m[tid]) * rsqrtf(bn1v[tid] + BN_EPS) * bn1g[tid] + bn1b[tid];
        z1s[tid] = fmaxf(acc, 0.0f);
    }
    __syncthreads();
    if (tid < H2 / 2) {
        float acc = h2b[tid];
#pragma unroll
        for (int j = 0; j < H2; ++j) acc += z1s[j] * h2w[j * (H2 / 2) + tid];
        acc = (acc - bn2m[tid]) * rsqrtf(bn2v[tid] + BN_EPS) * bn2g[tid] + bn2b[tid];
        z2s[tid] = fmaxf(acc, 0.0f);
    }
    __syncthreads();
    if (tid == 0) {
        float acc = h3b[0];
#pragma unroll
        for (int j = 0; j < H2 / 2; ++j) acc += z2s[j] * h3w[j];
        out[b] = acc;
    }
}

// ---------------------------------------------------------------- launch
extern "C" void kernel_launch(void* const* d_in, const int* in_sizes, int n_in,
                              void* d_out, int out_size, void* d_ws, size_t ws_size,
                              hipStream_t stream)
{
    const float* x         = (const float*)d_in[0];
    const int*   ei        = (const int*)d_in[1];
    const float* edge_attr = (const float*)d_in[2];
    const int*   batch     = (const int*)d_in[3];
    const float* e1_w1 = (const float*)d_in[4];
    const float* e1_b1 = (const float*)d_in[5];
    const float* e1_w2 = (const float*)d_in[6];
    const float* e1_b2 = (const float*)d_in[7];
    const float* root1 = (const float*)d_in[8];
    const float* bias1 = (const float*)d_in[9];
    const float* e2_w1 = (const float*)d_in[10];
    const float* e2_b1 = (const float*)d_in[11];
    const float* e2_w2 = (const float*)d_in[12];
    const float* e2_b2 = (const float*)d_in[13];
    const float* root2 = (const float*)d_in[14];
    const float* bias2 = (const float*)d_in[15];
    const float* h1w = (const float*)d_in[16];
    const float* h1b = (const float*)d_in[17];
    const float* bn1g = (const float*)d_in[18];
    const float* bn1b = (const float*)d_in[19];
    const float* bn1m = (const float*)d_in[20];
    const float* bn1v = (const float*)d_in[21];
    const float* h2w = (const float*)d_in[22];
    const float* h2b = (const float*)d_in[23];
    const float* bn2g = (const float*)d_in[24];
    const float* bn2b = (const float*)d_in[25];
    const float* bn2m = (const float*)d_in[26];
    const float* bn2v = (const float*)d_in[27];
    const float* h3w = (const float*)d_in[28];
    const float* h3b = (const float*)d_in[29];
    float* out = (float*)d_out;

    float* ws = (float*)d_ws;
    uint32* hpk1 = (uint32*)ws;                          // E*32 u32 (aliased as h2o later)
    uint32* hpk2 = hpk1 + (size_t)N_EDGES * EHID;        // E*32 u32
    float* out1  = (float*)(hpk2 + (size_t)N_EDGES * EHID); // N*H1
    float* agg1  = out1 + (size_t)N_NODES * H1;          // N*H1
    float* agg2  = agg1 + (size_t)N_NODES * H1;          // N*H2
    float* gmaxb = agg2 + (size_t)N_NODES * H2;          // NGRAPH*H2
    float* gsumb = gmaxb + NGRAPH * H2;                  // NGRAPH*H2
    float* gcntb = gsumb + NGRAPH * H2;                  // NGRAPH (+pad)
    unsigned short* w2h1 = (unsigned short*)(gcntb + 256);   // H1*KTOT f16
    unsigned short* w2h2 = w2h1 + (size_t)H1 * KTOT;         // H2*KTOT f16
    float* h2o = (float*)hpk1;                           // N*H2 f32, aliases hpk1 (dead after msg1)

    const int* srcp = ei;
    const int* dstp = ei + N_EDGES;

    prologue_kernel<<<EH_BLOCKS + PREP_BLOCKS + INIT_BLOCKS, 256, 0, stream>>>(
        edge_attr, e1_w1, e1_b1, e2_w1, e2_b1, e1_w2, e1_b2, e2_w2, e2_b2,
        hpk1, hpk2, w2h1, w2h2, agg1, agg2, gmaxb, gsumb, gcntb);

    msg_v4_kernel<H1><<<MSG_BLOCKS, 256, 0, stream>>>(x, hpk1, srcp, dstp, w2h1, agg1);
    node_update_kernel<H1, true><<<2048, 256, 0, stream>>>(x, root1, agg1, bias1, out1);

    msg_v4_kernel<H2><<<MSG_BLOCKS, 256, 0, stream>>>(out1, hpk2, srcp, dstp, w2h2, agg2);
    node_update_kernel<H2, false><<<2048, 256, 0, stream>>>(out1, root2, agg2, bias2, h2o);

    pool_scan_kernel<<<(N_NODES + 63) / 64, 256, 0, stream>>>(h2o, batch, gmaxb, gsumb, gcntb);
    head_kernel<<<NGRAPH, 128, 0, stream>>>(gmaxb, gsumb, gcntb,
                                            h1w, h1b, bn1g, bn1b, bn1m, bn1v,
                                            h2w, h2b, bn2g, bn2b, bn2m, bn2v,
                                            h3w, h3b, out);
}